// Round 8
// baseline (471.401 us; speedup 1.0000x reference)
//
#include <hip/hip_runtime.h>
#include <hip/hip_bf16.h>

#define DEVFN __device__ __forceinline__

typedef __attribute__((ext_vector_type(8))) short bf16x8;
typedef __attribute__((ext_vector_type(4))) float f32x4;

constexpr int T = 128, C = 8, K = 9;
constexpr int HW = 1024;   // 32x32
constexpr int BT = 512;    // B*T images
constexpr size_t Z_SIZE = (size_t)BT * C * HW;

// LDS tile geometry: 10 site-rows (R0-1..R0+8) x 34 sites
constexpr int SROW64 = 34 * 128;   // 4352 B (64ch bf16 per site)
constexpr int TILE64 = 10 * SROW64;  // 43520 B
constexpr int SROW32 = 34 * 64;    // 2176 B (32ch bf16 per site)
constexpr int TILE32 = 10 * SROW32;  // 21760 B

// fragment-packed weights (bf16 element offsets): [tap][c][mt][lane][8]
constexpr int WP_IN = 0;            // 9*1*4*64*8 = 18432
constexpr int WP_W1_0 = 18432;      // 9*2*4*64*8 = 36864
constexpr int WP_W2_0 = 55296;
constexpr int WP_W1_1 = 92160;
constexpr int WP_W2_1 = 129024;
constexpr int WP_OUT = 165888;      // 9*2*1*64*8 = 9216
constexpr int WP_TOT = 175104;

DEVFN ushort f2bs(float x) {
  __hip_bfloat16 h = __float2bfloat16(x);
  ushort u;
  __builtin_memcpy(&u, &h, 2);
  return u;
}
DEVFN float bs2f(ushort u) {
  __hip_bfloat16 h;
  __builtin_memcpy(&h, &u, 2);
  return __bfloat162float(h);
}

// idx rows sorted ascending; branchless count, no local array (rule #20).
DEVFN void interp_params(const int* __restrict__ idx, int b, int t,
                         int& t0, int& t1, float& ar, float& a) {
  const int* ib = idx + b * K;
  int cnt = 0;
#pragma unroll
  for (int k = 0; k < K; ++k) cnt += (ib[k] <= t) ? 1 : 0;
  int seg = min(max(cnt - 1, 0), K - 2);
  t0 = ib[seg];
  t1 = ib[seg + 1];
  ar = (float)(t - t0) / (float)max(t1 - t0, 1);
  a = fminf(fmaxf(ar, 0.f), 1.f);
}

// ---------------------------------------------------------------------------
// weight pack: fragment order [tap][c][mt][lane][8]:
//   element = W[oc = mt*16 + (lane&15)][ic = c*32 + (lane>>4)*8 + e][tap]
// ---------------------------------------------------------------------------
__global__ __launch_bounds__(256) void pack_weights(
    const float* __restrict__ w_in, const float* __restrict__ w1s,
    const float* __restrict__ w2s, const float* __restrict__ w_out,
    __hip_bfloat16* __restrict__ wp) {
  int e = blockIdx.x * 256 + threadIdx.x;
  if (e >= WP_TOT) return;
  float v;
  if (e < WP_W1_0) {  // conv_in: [9][1][4][64][8], IC=32 (25 real)
    int tap = e / 2048;
    int r2 = e % 2048;
    int mt = r2 / 512;
    int lane = (r2 / 8) & 63;
    int el = e & 7;
    int oc = mt * 16 + (lane & 15);
    int ic = (lane >> 4) * 8 + el;
    v = (ic < 25) ? w_in[((size_t)oc * 25 + ic) * 9 + tap] : 0.f;
  } else if (e < WP_OUT) {  // 4 x conv64: [9][2][4][64][8]
    int r = e - WP_W1_0;
    int layer = r / 36864;  // 0:w1 blk0, 1:w2 blk0, 2:w1 blk1, 3:w2 blk1
    int r2 = r % 36864;
    int tap = r2 / 4096;
    int c = (r2 / 2048) & 1;
    int mt = (r2 / 512) & 3;
    int lane = (r2 / 8) & 63;
    int el = r2 & 7;
    int oc = mt * 16 + (lane & 15);
    int ic = c * 32 + (lane >> 4) * 8 + el;
    const float* src = (layer & 1) ? w2s : w1s;
    int blk = layer >> 1;
    v = src[(((size_t)blk * 64 + oc) * 64 + ic) * 9 + tap];
  } else {  // final: [9][2][1][64][8], OC=16 (9 real)
    int r2 = e - WP_OUT;
    int tap = r2 / 1024;
    int c = (r2 / 512) & 1;
    int lane = (r2 / 8) & 63;
    int el = r2 & 7;
    int oc = lane & 15;
    int ic = c * 32 + (lane >> 4) * 8 + el;
    v = (oc < 9) ? w_out[((size_t)oc * 64 + ic) * 9 + tap] : 0.f;
  }
  wp[e] = __float2bfloat16(v);
}

// ---------------------------------------------------------------------------
// conv inner loop: zero-halo LDS tile, precomputed swizzled bases, j-batched
// bv (8 ds_read_b128 per (c,d) feed MT*3*4 MFMAs). acc[MT][4], wave = 2 rows.
// ---------------------------------------------------------------------------
template <int CK, int MT, int SITE_B>
DEVFN void conv_compute(const char* sBuf, const __hip_bfloat16* __restrict__ wpf,
                        const int (&base)[3][CK], int lane,
                        f32x4 (&acc)[MT][4]) {
  constexpr int ROW = 34 * SITE_B;
  constexpr int XH = 16 * SITE_B;
#pragma unroll
  for (int c = 0; c < CK; ++c) {
#pragma unroll
    for (int d = 0; d < 3; ++d) {
      bf16x8 bv[4][2];
#pragma unroll
      for (int j = 0; j < 4; ++j)
#pragma unroll
        for (int xh = 0; xh < 2; ++xh)
          bv[j][xh] = *(const bf16x8*)(sBuf + base[d][c] + xh * XH + j * ROW);
#pragma unroll
      for (int mt = 0; mt < MT; ++mt) {
#pragma unroll
        for (int dyi = 0; dyi < 3; ++dyi) {
          const int tap = dyi * 3 + d;
          bf16x8 av =
              *(const bf16x8*)(wpf + (((tap * CK + c) * MT + mt) * 64 + lane) * 8);
#pragma unroll
          for (int oy = 0; oy < 2; ++oy)
#pragma unroll
            for (int xh = 0; xh < 2; ++xh)
              acc[mt][oy * 2 + xh] = __builtin_amdgcn_mfma_f32_16x16x32_bf16(
                  av, bv[oy + dyi][xh], acc[mt][oy * 2 + xh], 0, 0, 0);
        }
      }
    }
  }
}

// ---------------------------------------------------------------------------
// conv64: one dispatch per layer. Block = 256 thr (4 waves), 8 output rows.
// Stage rows R0-1..R0+8 (zero-padded halo) into 43.5 KB LDS -> 3 blocks/CU.
// ---------------------------------------------------------------------------
template <bool SILU, bool RESID>
__global__ __launch_bounds__(256) void conv64_t(
    const __hip_bfloat16* __restrict__ in,   // [512][1024][64] px-major
    const __hip_bfloat16* __restrict__ wpf,  // fragment-packed [9][2][4][64][8]
    const float* __restrict__ bias,          // [64]
    __hip_bfloat16* __restrict__ out) {      // [512][1024][64]
  __shared__ __align__(16) char sBuf[TILE64];

  const int img = blockIdx.x;
  const int R0 = blockIdx.y * 8;
  const int tid = threadIdx.x;
  const int lane = tid & 63, wv = tid >> 6, g = lane >> 4, ln = lane & 15;
  const int r0L = wv * 2;
  const size_t imgBase = (size_t)img * HW * 64;

  // ---- stage: 2720 x 16B slots (10 rows x 34 sites x 8 slots), swizzled ----
  for (int e = tid; e < 2720; e += 256) {
    int srow = e / 272;
    int rem = e - srow * 272;
    int sx = rem >> 3, slot = rem & 7;
    int gy = R0 - 1 + srow, gx = sx - 1;
    int4 v = int4{0, 0, 0, 0};
    if (((unsigned)gy < 32u) & ((unsigned)gx < 32u))
      v = *(const int4*)(in + imgBase + (size_t)(gy * 32 + gx) * 64 + slot * 8);
    int dst = (srow * 34 + sx) * 128 + ((slot * 16) ^ ((sx & 7) << 4));
    *(int4*)(sBuf + dst) = v;
  }
  __syncthreads();

  int base[3][2];
#pragma unroll
  for (int d = 0; d < 3; ++d)
#pragma unroll
    for (int c = 0; c < 2; ++c)
      base[d][c] = r0L * SROW64 +
                   (((ln + d) * 128 + c * 64 + g * 16) ^ (((ln + d) & 7) << 4));

  f32x4 acc[4][4];
#pragma unroll
  for (int mt = 0; mt < 4; ++mt)
#pragma unroll
    for (int nt = 0; nt < 4; ++nt) acc[mt][nt] = (f32x4)0.f;

  conv_compute<2, 4, 128>(sBuf, wpf, base, lane, acc);

  // ---- epilogue: +bias, silu / residual-add (in-place out), store bf16 ----
#pragma unroll
  for (int mt = 0; mt < 4; ++mt) {
    const float4 bv4 = *(const float4*)(bias + mt * 16 + g * 4);
#pragma unroll
    for (int nt = 0; nt < 4; ++nt) {
      const int px = (R0 + r0L + (nt >> 1)) * 32 + (nt & 1) * 16 + ln;
      __hip_bfloat16* op = (__hip_bfloat16*)(out + imgBase + (size_t)px * 64 +
                                             mt * 16 + g * 4);
      float v0 = acc[mt][nt][0] + bv4.x;
      float v1 = acc[mt][nt][1] + bv4.y;
      float v2 = acc[mt][nt][2] + bv4.z;
      float v3 = acc[mt][nt][3] + bv4.w;
      if (SILU) {
        v0 = v0 / (1.f + expf(-v0));
        v1 = v1 / (1.f + expf(-v1));
        v2 = v2 / (1.f + expf(-v2));
        v3 = v3 / (1.f + expf(-v3));
      }
      if (RESID) {
        ushort4 h = *(const ushort4*)op;
        v0 += bs2f(h.x);
        v1 += bs2f(h.y);
        v2 += bs2f(h.z);
        v3 += bs2f(h.w);
      }
      ushort4 s;
      s.x = f2bs(v0);
      s.y = f2bs(v1);
      s.z = f2bs(v2);
      s.w = f2bs(v3);
      *(ushort4*)op = s;
    }
  }
}

// ---------------------------------------------------------------------------
// conv_in: prep fused into staging (z_base/z0/z1/alpha from fp32 latents).
// IC=32 tile (21.8 KB), swizzle key = (sx&3)<<4 (64 B sites).
// ---------------------------------------------------------------------------
__global__ __launch_bounds__(256) void conv_in_t(
    const float* __restrict__ latents, const int* __restrict__ idx,
    const __hip_bfloat16* __restrict__ wpf,  // [9][1][4][64][8]
    const float* __restrict__ bias,          // [64]
    __hip_bfloat16* __restrict__ out) {      // [512][1024][64]
  __shared__ __align__(16) char sBuf[TILE32];

  const int img = blockIdx.x;
  const int R0 = blockIdx.y * 8;
  const int tid = threadIdx.x;
  const int lane = tid & 63, wv = tid >> 6, g = lane >> 4, ln = lane & 15;
  const int r0L = wv * 2;
  const int b = img >> 7, t = img & 127;

  int t0, t1;
  float ar, a;
  interp_params(idx, b, t, t0, t1, ar, a);
  const float* z0p = latents + ((size_t)b * T + t0) * C * HW;
  const float* z1p = latents + ((size_t)b * T + t1) * C * HW;
  const ushort ab = f2bs(a);

  // ---- stage 340 sites: {z_base, z0, z1, alpha} packed bf16, swizzled ----
  for (int e = tid; e < 340; e += 256) {
    int srow = e / 34, sx = e - srow * 34;
    int gy = R0 - 1 + srow, gx = sx - 1;
    char* sp = sBuf + srow * SROW32 + sx * 64;
    const int key = (sx & 3) << 4;
    if (((unsigned)gy < 32u) & ((unsigned)gx < 32u)) {
      int p = gy * 32 + gx;
      float v0[8], v1[8];
#pragma unroll
      for (int c2 = 0; c2 < 8; ++c2) {
        v0[c2] = z0p[c2 * HW + p];
        v1[c2] = z1p[c2 * HW + p];
      }
      ushort u[8];
      int4 q;
#pragma unroll
      for (int c2 = 0; c2 < 8; ++c2) u[c2] = f2bs((1.f - a) * v0[c2] + a * v1[c2]);
      q.x = (int)u[0] | ((int)u[1] << 16); q.y = (int)u[2] | ((int)u[3] << 16);
      q.z = (int)u[4] | ((int)u[5] << 16); q.w = (int)u[6] | ((int)u[7] << 16);
      *(int4*)(sp + (0 ^ key)) = q;
#pragma unroll
      for (int c2 = 0; c2 < 8; ++c2) u[c2] = f2bs(v0[c2]);
      q.x = (int)u[0] | ((int)u[1] << 16); q.y = (int)u[2] | ((int)u[3] << 16);
      q.z = (int)u[4] | ((int)u[5] << 16); q.w = (int)u[6] | ((int)u[7] << 16);
      *(int4*)(sp + (16 ^ key)) = q;
#pragma unroll
      for (int c2 = 0; c2 < 8; ++c2) u[c2] = f2bs(v1[c2]);
      q.x = (int)u[0] | ((int)u[1] << 16); q.y = (int)u[2] | ((int)u[3] << 16);
      q.z = (int)u[4] | ((int)u[5] << 16); q.w = (int)u[6] | ((int)u[7] << 16);
      *(int4*)(sp + (32 ^ key)) = q;
      q.x = (int)ab; q.y = 0; q.z = 0; q.w = 0;
      *(int4*)(sp + (48 ^ key)) = q;
    } else {
      int4 z = int4{0, 0, 0, 0};
#pragma unroll
      for (int s = 0; s < 4; ++s) *(int4*)(sp + ((s * 16) ^ key)) = z;
    }
  }
  __syncthreads();

  int base[3][1];
#pragma unroll
  for (int d = 0; d < 3; ++d)
    base[d][0] =
        r0L * SROW32 + (((ln + d) * 64 + g * 16) ^ (((ln + d) & 3) << 4));

  f32x4 acc[4][4];
#pragma unroll
  for (int mt = 0; mt < 4; ++mt)
#pragma unroll
    for (int nt = 0; nt < 4; ++nt) acc[mt][nt] = (f32x4)0.f;

  conv_compute<1, 4, 64>(sBuf, wpf, base, lane, acc);

  const size_t imgBase = (size_t)img * HW * 64;
#pragma unroll
  for (int mt = 0; mt < 4; ++mt) {
    const float4 bv4 = *(const float4*)(bias + mt * 16 + g * 4);
#pragma unroll
    for (int nt = 0; nt < 4; ++nt) {
      const int px = (R0 + r0L + (nt >> 1)) * 32 + (nt & 1) * 16 + ln;
      float v0 = acc[mt][nt][0] + bv4.x;
      float v1 = acc[mt][nt][1] + bv4.y;
      float v2 = acc[mt][nt][2] + bv4.z;
      float v3 = acc[mt][nt][3] + bv4.w;
      ushort4 s;
      s.x = f2bs(v0 / (1.f + expf(-v0)));
      s.y = f2bs(v1 / (1.f + expf(-v1)));
      s.z = f2bs(v2 / (1.f + expf(-v2)));
      s.w = f2bs(v3 / (1.f + expf(-v3)));
      *(ushort4*)(out + imgBase + (size_t)px * 64 + mt * 16 + g * 4) = s;
    }
  }
}

// ---------------------------------------------------------------------------
// final conv (64->16, 9 real) fused with z_hat / conf epilogue.
// ---------------------------------------------------------------------------
__global__ __launch_bounds__(256) void conv_final_t(
    const __hip_bfloat16* __restrict__ in,   // H [512][1024][64]
    const __hip_bfloat16* __restrict__ wpf,  // [9][2][1][64][8]
    const float* __restrict__ bias,          // [9]
    const float* __restrict__ latents, const int* __restrict__ idx,
    float* __restrict__ dout) {
  __shared__ __align__(16) char sBuf[TILE64];
  __shared__ float sOut[256][17];

  const int img = blockIdx.x;
  const int R0 = blockIdx.y * 8;
  const int tid = threadIdx.x;
  const int lane = tid & 63, wv = tid >> 6, g = lane >> 4, ln = lane & 15;
  const int r0L = wv * 2;
  const int b = img >> 7, t = img & 127;
  const size_t imgBase = (size_t)img * HW * 64;

  int t0, t1;
  float ar, a;
  interp_params(idx, b, t, t0, t1, ar, a);
  const float* z0p = latents + ((size_t)b * T + t0) * C * HW;
  const float* z1p = latents + ((size_t)b * T + t1) * C * HW;

  for (int e = tid; e < 2720; e += 256) {
    int srow = e / 272;
    int rem = e - srow * 272;
    int sx = rem >> 3, slot = rem & 7;
    int gy = R0 - 1 + srow, gx = sx - 1;
    int4 v = int4{0, 0, 0, 0};
    if (((unsigned)gy < 32u) & ((unsigned)gx < 32u))
      v = *(const int4*)(in + imgBase + (size_t)(gy * 32 + gx) * 64 + slot * 8);
    int dst = (srow * 34 + sx) * 128 + ((slot * 16) ^ ((sx & 7) << 4));
    *(int4*)(sBuf + dst) = v;
  }
  __syncthreads();

  int base[3][2];
#pragma unroll
  for (int d = 0; d < 3; ++d)
#pragma unroll
    for (int c = 0; c < 2; ++c)
      base[d][c] = r0L * SROW64 +
                   (((ln + d) * 128 + c * 64 + g * 16) ^ (((ln + d) & 7) << 4));

  f32x4 acc[1][4];
#pragma unroll
  for (int nt = 0; nt < 4; ++nt) acc[0][nt] = (f32x4)0.f;

  conv_compute<2, 1, 128>(sBuf, wpf, base, lane, acc);

  // acc -> sOut[local px][oc] (+bias)
#pragma unroll
  for (int nt = 0; nt < 4; ++nt) {
    const int pxl = (r0L + (nt >> 1)) * 32 + (nt & 1) * 16 + ln;
#pragma unroll
    for (int r = 0; r < 4; ++r) {
      const int oc = g * 4 + r;
      sOut[pxl][oc] = acc[0][nt][r] + ((oc < 9) ? bias[oc] : 0.f);
    }
  }
  __syncthreads();

  // fused z_hat / conf epilogue: one thread per pixel of the 8-row strip
  const bool interior = (ar > 0.f) && (ar < 1.f);
  const float aa = a * (1.f - a);
  const int px = R0 * 32 + tid;
#pragma unroll
  for (int c2 = 0; c2 < 8; ++c2) {
    float res = sOut[tid][c2];
    float v0 = z0p[c2 * HW + px], v1 = z1p[c2 * HW + px];
    float zb = (1.f - a) * v0 + a * v1;
    dout[((size_t)img * C + c2) * HW + px] = zb + aa * res;
  }
  float unc = 1.f / (1.f + expf(-sOut[tid][8]));
  float conf = interior ? fminf(fmaxf(1.f - unc, 0.f), 1.f) : 1.f;
  dout[Z_SIZE + (size_t)img * HW + px] = conf;
}

// ---------------------------------------------------------------------------
// launch: pack + 6 conv dispatches, A/B ping-pong in ws
// ---------------------------------------------------------------------------
extern "C" void kernel_launch(void* const* d_in, const int* in_sizes, int n_in,
                              void* d_out, int out_size, void* d_ws,
                              size_t ws_size, hipStream_t stream) {
  const float* latents = (const float*)d_in[0];
  const int* idx = (const int*)d_in[1];
  const float* w_in = (const float*)d_in[2];
  const float* b_in = (const float*)d_in[3];
  const float* w1s = (const float*)d_in[4];
  const float* b1s = (const float*)d_in[5];
  const float* w2s = (const float*)d_in[6];
  const float* b2s = (const float*)d_in[7];
  const float* w_out = (const float*)d_in[8];
  const float* b_out = (const float*)d_in[9];
  float* dout = (float*)d_out;

  char* ws = (char*)d_ws;
  __hip_bfloat16* A = (__hip_bfloat16*)ws;                        // 64 MiB
  __hip_bfloat16* Bb = (__hip_bfloat16*)(ws + (size_t)67108864);  // 64 MiB
  __hip_bfloat16* wpk = (__hip_bfloat16*)(ws + (size_t)134217728);

  pack_weights<<<(WP_TOT + 255) / 256, 256, 0, stream>>>(w_in, w1s, w2s, w_out,
                                                         wpk);

  dim3 grid(BT, 4);
  conv_in_t<<<grid, 256, 0, stream>>>(latents, idx, wpk + WP_IN, b_in, A);

  conv64_t<true, false><<<grid, 256, 0, stream>>>(A, wpk + WP_W1_0, b1s, Bb);
  conv64_t<false, true><<<grid, 256, 0, stream>>>(Bb, wpk + WP_W2_0, b2s, A);
  conv64_t<true, false><<<grid, 256, 0, stream>>>(A, wpk + WP_W1_1, b1s + 64, Bb);
  conv64_t<false, true><<<grid, 256, 0, stream>>>(Bb, wpk + WP_W2_1, b2s + 64, A);

  conv_final_t<<<grid, 256, 0, stream>>>(A, wpk + WP_OUT, b_out, latents, idx,
                                         dout);
}